// Round 6
// baseline (202.844 us; speedup 1.0000x reference)
//
#include <hip/hip_runtime.h>

#define NT 8
#define NY 32
#define NX 32
#define NN 1024  // NY*NX

typedef __attribute__((ext_vector_type(4))) float f32x4;

// Stencil coefficients of M = I + A for one node. c[(ry+1)*3+(rx+1)] is the
// coefficient toward target offset (ry,rx); zeroed when the TARGET node falls
// off-grid (matches reference `valid` masking on the column node).
__device__ __forceinline__ void node_coefs(const float* __restrict__ kap,
                                           const float* __restrict__ m,
                                           const float* __restrict__ H,
                                           const float* __restrict__ tau,
                                           int b, int node, int tc,
                                           int iy, int ix,
                                           float* c /*[9]*/, float& w) {
    const int base = node * NT + tc;                 // [.., node, t] layout, last dim NT
    const float kp  = kap[(b * NN) * NT + base];
    const float m1  = m[((b * 2 + 0) * NN) * NT + base];
    const float m2  = m[((b * 2 + 1) * NN) * NT + base];
    const float h11 = H[((b * 4 + 0) * NN) * NT + base];
    const float h12 = H[((b * 4 + 1) * NN) * NT + base];
    const float h22 = H[((b * 4 + 3) * NN) * NT + base];
    const float tv  = tau[(b * NN) * NT + base];
    w = 1.0f / (tv * tv);

    const float cxy = 0.5f * h12;
    const bool ym = iy > 0, yp = iy < NY - 1;
    const bool xm = ix > 0, xp = ix < NX - 1;

    c[4] = 1.0f + kp * kp + 2.0f * h11 + 2.0f * h22;
    c[0] = (ym && xm) ? -cxy               : 0.0f;
    c[1] =  ym        ? (-h22 - 0.5f * m2) : 0.0f;
    c[2] = (ym && xp) ?  cxy               : 0.0f;
    c[3] =  xm        ? (-h11 - 0.5f * m1) : 0.0f;
    c[5] =  xp        ? (-h11 + 0.5f * m1) : 0.0f;
    c[6] = (yp && xm) ?  cxy               : 0.0f;
    c[7] =  yp        ? (-h22 + 0.5f * m2) : 0.0f;
    c[8] = (yp && xp) ? -cxy               : 0.0f;
}

// Fill-shaped fused kernel. One block per contiguous 256KB chunk of the output
// (16 chunks per [N,N] matrix; chunks never straddle matrices). Thread tid owns
// quad tid of each of the chunk's 64 rows: every wave store is 1KB contiguous,
// the block streams its chunk in pure address order (vendor-fill shape).
// Band values are precomputed into LDS; most threads stream pure zeros.
__global__ __launch_bounds__(256) void spde_chunks(const float* __restrict__ kap,
                                                   const float* __restrict__ m,
                                                   const float* __restrict__ H,
                                                   const float* __restrict__ tau,
                                                   float* __restrict__ out) {
    __shared__ float sc[4][34][9];   // coefs of node (y0-1+ly, lx-1); halo zeroed
    __shared__ float sw[4][34];      // w at those nodes (0 off-grid)
    __shared__ float vals[64][25];   // D: 25/row; L/U: first 9/row

    const int chunk = blockIdx.x;
    const int mat   = chunk >> 4;          // 16 chunks per matrix
    const int j0    = (chunk & 15) * 64;   // first matrix-row of this chunk
    const int tt    = mat & 7;             // time index within the matrix group
    const int c     = (mat >> 3) % 3;      // 0=D, 1=lower, 2=upper
    const int b     = mat / 24;
    const int tid   = threadIdx.x;
    const int y0    = j0 >> 5;             // first grid-row (rows y0, y0+1)

    f32x4* const base = (f32x4*)out + ((size_t)chunk << 14) + tid;

    // lower[0] and upper[7] are identically zero: pure streaming fill.
    const bool zeroChunk = (c == 1 && tt == 0) || (c == 2 && tt == NT - 1);
    if (zeroChunk) {
        const f32x4 z = {0.f, 0.f, 0.f, 0.f};
        #pragma unroll
        for (int k = 0; k < 64; ++k) base[k * 256] = z;
        return;
    }

    const int tc = (c == 2) ? tt + 1 : tt;   // source time for the coefficients

    // phase A: coefs for grid rows y0-1..y0+2, x = -1..32 (136 nodes)
    if (tid < 136) {
        const int ly = tid / 34, lx = tid % 34;
        const int iy = y0 + ly - 1, ix = lx - 1;
        float cf[9];
        float w = 0.0f;
        if (iy >= 0 && iy < NY && ix >= 0 && ix < NX) {
            node_coefs(kap, m, H, tau, b, iy * NX + ix, tc, iy, ix, cf, w);
        } else {
            #pragma unroll
            for (int q = 0; q < 9; ++q) cf[q] = 0.0f;
        }
        #pragma unroll
        for (int q = 0; q < 9; ++q) sc[ly][lx][q] = cf[q];
        sw[ly][lx] = w;
    }
    __syncthreads();

    // phase B: band values for the chunk's 64 rows
    if (c == 0) {            // D: sum_i w[i] M[i,j] M[i,k]  (+ w_{t+1}[j] on diag)
        #pragma unroll
        for (int pass = 0; pass < 7; ++pass) {
            const int e = tid + pass * 256;
            if (e < 1600) {
                const int k = e / 25, l = e % 25;
                const int dy = l / 5 - 2, dx = l % 5 - 2;
                const int ry = k >> 5, jx = k & 31;     // jy = y0 + ry
                float acc = 0.0f;
                #pragma unroll
                for (int d = 0; d < 9; ++d) {           // source rows i = j + off_d
                    const int ey = d / 3 - 1, ex = d % 3 - 1;
                    const int r2y = dy - ey, r2x = dx - ex;
                    if (r2y >= -1 && r2y <= 1 && r2x >= -1 && r2x <= 1) {
                        const float* ci = sc[ry + 1 + ey][jx + 1 + ex];
                        acc += sw[ry + 1 + ey][jx + 1 + ex] * ci[8 - d]
                                                            * ci[(r2y + 1) * 3 + (r2x + 1)];
                    }
                }
                if (l == 12 && tt < NT - 1) {
                    const int j = j0 + k;
                    const float tv = tau[((size_t)b * NN + j) * NT + (tt + 1)];
                    acc += 1.0f / (tv * tv);
                }
                vals[k][l] = acc;
            }
        }
    } else if (c == 1) {     // lower[tt], tt>=1: row j, col i=j+off_d : -w[i] M[i,j]
        #pragma unroll
        for (int pass = 0; pass < 3; ++pass) {
            const int e = tid + pass * 256;
            if (e < 576) {
                const int k = e / 9, d = e % 9;
                const int ey = d / 3 - 1, ex = d % 3 - 1;
                const int ly = (k >> 5) + 1 + ey, lx = (k & 31) + 1 + ex;
                vals[k][d] = -sw[ly][lx] * sc[ly][lx][8 - d];
            }
        }
    } else {                 // upper[tt], tt<=6: row j, col j+off_q : -w_{tt+1}[j] M_{tt+1}[j,.]
        #pragma unroll
        for (int pass = 0; pass < 3; ++pass) {
            const int e = tid + pass * 256;
            if (e < 576) {
                const int k = e / 9, q = e % 9;
                const int ly = (k >> 5) + 1, lx = (k & 31) + 1;
                vals[k][q] = -sw[ly][lx] * sc[ly][lx][q];
            }
        }
    }
    __syncthreads();

    // phase C: stream the chunk in address order. Thread's output column is
    // fixed: (ky, kx0..kx0+3). Per half (32 rows of one grid-row jy), ddy is
    // thread-constant -> out-of-band threads run a pure zero-streaming loop.
    const int ky  = tid >> 3, kx0 = (tid & 7) * 4;
    const int R   = (c == 0) ? 2 : 1;
    const int nw  = 2 * R + 1;
    f32x4* p = base;
    #pragma unroll
    for (int h = 0; h < 2; ++h) {
        const int jy  = y0 + h;
        const int ddy = ky - jy;
        if (ddy < -R || ddy > R) {
            const f32x4 z = {0.f, 0.f, 0.f, 0.f};
            #pragma unroll
            for (int kk = 0; kk < 32; ++kk) p[kk * 256] = z;
        } else {
            const int rowoff = (ddy + R) * nw + R;   // + ddx gives the band index
            #pragma unroll
            for (int kk = 0; kk < 32; ++kk) {        // jx = kk
                f32x4 v = {0.f, 0.f, 0.f, 0.f};
                #pragma unroll
                for (int cq = 0; cq < 4; ++cq) {
                    const int ddx = kx0 + cq - kk;
                    if (ddx >= -R && ddx <= R) v[cq] = vals[h * 32 + kk][rowoff + ddx];
                }
                p[kk * 256] = v;
            }
        }
        p += 32 * 256;
    }
}

extern "C" void kernel_launch(void* const* d_in, const int* in_sizes, int n_in,
                              void* d_out, int out_size, void* d_ws, size_t ws_size,
                              hipStream_t stream) {
    (void)n_in; (void)d_ws; (void)ws_size; (void)out_size;
    const float* kap = (const float*)d_in[0];  // [n_b,1,N,NT]
    const float* m   = (const float*)d_in[1];  // [n_b,2,N,NT]
    const float* H   = (const float*)d_in[2];  // [n_b,2,2,N,NT]
    const float* tau = (const float*)d_in[3];  // [n_b,1,N,NT]
    float* out = (float*)d_out;                // [n_b,3,NT,N,N]

    const int n_b = in_sizes[0] / (NN * NT);
    const int grid = n_b * 3 * NT * 16;        // one block per 256KB chunk
    spde_chunks<<<grid, 256, 0, stream>>>(kap, m, H, tau, out);
}

// Round 7
// 189.478 us; speedup vs baseline: 1.0705x; 1.0705x over previous
//
#include <hip/hip_runtime.h>

#define NT 8
#define NY 32
#define NX 32
#define NN 1024  // NY*NX

typedef __attribute__((ext_vector_type(4))) float f32x4;

// Stencil coefficients of M = I + A for one node. c[(ry+1)*3+(rx+1)] is the
// coefficient toward target offset (ry,rx); zeroed when the TARGET node falls
// off-grid (matches reference `valid` masking on the column node).
__device__ __forceinline__ void node_coefs(const float* __restrict__ kap,
                                           const float* __restrict__ m,
                                           const float* __restrict__ H,
                                           const float* __restrict__ tau,
                                           int b, int node, int tc,
                                           int iy, int ix,
                                           float* c /*[9]*/, float& w) {
    const int base = node * NT + tc;                 // [.., node, t] layout, last dim NT
    const float kp  = kap[(b * NN) * NT + base];
    const float m1  = m[((b * 2 + 0) * NN) * NT + base];
    const float m2  = m[((b * 2 + 1) * NN) * NT + base];
    const float h11 = H[((b * 4 + 0) * NN) * NT + base];
    const float h12 = H[((b * 4 + 1) * NN) * NT + base];
    const float h22 = H[((b * 4 + 3) * NN) * NT + base];
    const float tv  = tau[(b * NN) * NT + base];
    w = 1.0f / (tv * tv);

    const float cxy = 0.5f * h12;
    const bool ym = iy > 0, yp = iy < NY - 1;
    const bool xm = ix > 0, xp = ix < NX - 1;

    c[4] = 1.0f + kp * kp + 2.0f * h11 + 2.0f * h22;
    c[0] = (ym && xm) ? -cxy               : 0.0f;
    c[1] =  ym        ? (-h22 - 0.5f * m2) : 0.0f;
    c[2] = (ym && xp) ?  cxy               : 0.0f;
    c[3] =  xm        ? (-h11 - 0.5f * m1) : 0.0f;
    c[5] =  xp        ? (-h11 + 0.5f * m1) : 0.0f;
    c[6] = (yp && xm) ?  cxy               : 0.0f;
    c[7] =  yp        ? (-h22 + 0.5f * m2) : 0.0f;
    c[8] = (yp && xp) ? -cxy               : 0.0f;
}

// Role-split scatter over a pre-zeroed output. One block per (b, t, jy, role):
//   role 0 (D):  coef halo (3x34) -> 800 band values -> 5 store passes
//   role 1 (L):  coef halo (3x34) -> inline values   -> 3 store passes (t>=1)
//   role 2 (U):  OWN-ROW coefs only (32 nodes), values folded into phase A,
//                one barrier, 3 store passes (writes upper[t] from time t+1)
// All stores are full 128B ky-segments (8 lanes x float4). L[0]/U[7] remain
// memset-zero (those blocks exit immediately).
__global__ __launch_bounds__(256) void spde_scatter3(const float* __restrict__ kap,
                                                     const float* __restrict__ m,
                                                     const float* __restrict__ H,
                                                     const float* __restrict__ tau,
                                                     float* __restrict__ out) {
    __shared__ float sc[3][34][9];   // coefs of node (jy-1+ly, lx-1); halo zeroed
    __shared__ float sw[3][34];      // w at those nodes (0 off-grid)
    __shared__ float valsD[32][25];  // D values; U role reuses cols 0..8

    const int gb   = blockIdx.x;
    const int role = gb % 3;
    const int rest = gb / 3;         // (b*NT + t)*NY + jy, re-packed
    const int jy   = rest & 31;
    const int t    = (rest >> 5) & 7;
    const int b    = rest >> 8;
    const int tid  = threadIdx.x;

    if (role == 1 && t == 0) return;        // lower[0] is zero
    if (role == 2 && t == NT - 1) return;   // upper[7] is zero

    f32x4* const outq = (f32x4*)out;
    const int rowbase = jy * NX;

    if (role == 2) {
        // upper[t] row j: -w_{t+1}[j] * M_{t+1}[j,k] -- only node j's own coefs
        if (tid < 32) {
            float c[9];
            float w;
            node_coefs(kap, m, H, tau, b, jy * NX + tid, t + 1, jy, tid, c, w);
            #pragma unroll
            for (int q = 0; q < 9; ++q) valsD[tid][q] = -w * c[q];
        }
        __syncthreads();
        const size_t matU = ((size_t)(b * 3 + 2) * NT + t) << 18;
        #pragma unroll
        for (int pass = 0; pass < 3; ++pass) {
            const int idx = tid + pass * 256;
            const int jj = idx / 24, r = idx % 24;
            const int s = r >> 3, q = r & 7;
            const int ky = jy - 1 + s;
            if (ky >= 0 && ky < NY) {
                f32x4 v = {0.f, 0.f, 0.f, 0.f};
                #pragma unroll
                for (int cq = 0; cq < 4; ++cq) {
                    const int ddx = q * 4 + cq - jj;
                    if (ddx >= -1 && ddx <= 1) v[cq] = valsD[jj][s * 3 + (ddx + 1)];
                }
                outq[matU + ((size_t)(rowbase + jj) << 8) + ky * 8 + q] = v;
            }
        }
        return;
    }

    // roles D and L: coef halo for grid rows jy-1..jy+1, x = -1..32
    if (tid < 102) {
        const int ly = tid / 34, lx = tid % 34;
        const int iy = jy + ly - 1, ix = lx - 1;
        float c[9];
        float w = 0.0f;
        if (iy >= 0 && iy < NY && ix >= 0 && ix < NX) {
            node_coefs(kap, m, H, tau, b, iy * NX + ix, t, iy, ix, c, w);
        } else {
            #pragma unroll
            for (int q = 0; q < 9; ++q) c[q] = 0.0f;
        }
        #pragma unroll
        for (int q = 0; q < 9; ++q) sc[ly][lx][q] = c[q];
        sw[ly][lx] = w;
    }
    __syncthreads();

    if (role == 0) {
        // phase B: 800 D values (32 j x 25)
        #pragma unroll
        for (int pass = 0; pass < 4; ++pass) {
            const int e = tid + pass * 256;
            if (e < 800) {
                const int jj = e / 25, l = e % 25;
                const int dy = l / 5 - 2, dx = l % 5 - 2;
                float acc = 0.0f;
                #pragma unroll
                for (int d = 0; d < 9; ++d) {     // source rows i = j + off_d
                    const int ey = d / 3 - 1, ex = d % 3 - 1;
                    const int r2y = dy - ey, r2x = dx - ex;
                    if (r2y >= -1 && r2y <= 1 && r2x >= -1 && r2x <= 1) {
                        const float* ci = sc[ey + 1][jj + 1 + ex];
                        acc += sw[ey + 1][jj + 1 + ex] * ci[8 - d]
                                                       * ci[(r2y + 1) * 3 + (r2x + 1)];
                    }
                }
                if (l == 12 && t < NT - 1) {      // diagonal: + w_{t+1}[j]
                    const int j = rowbase + jj;
                    const float tv = tau[((size_t)b * NN + j) * NT + (t + 1)];
                    acc += 1.0f / (tv * tv);
                }
                valsD[jj][l] = acc;
            }
        }
        __syncthreads();
        const size_t matD = ((size_t)(b * 3 + 0) * NT + t) << 18;
        #pragma unroll
        for (int pass = 0; pass < 5; ++pass) {
            const int idx = tid + pass * 256;     // 1280 quads
            const int jj = idx / 40, r = idx % 40;
            const int s = r >> 3, q = r & 7;
            const int ky = jy - 2 + s;
            if (ky >= 0 && ky < NY) {
                f32x4 v = {0.f, 0.f, 0.f, 0.f};
                #pragma unroll
                for (int cq = 0; cq < 4; ++cq) {
                    const int ddx = q * 4 + cq - jj;
                    if (ddx >= -2 && ddx <= 2) v[cq] = valsD[jj][s * 5 + (ddx + 2)];
                }
                outq[matD + ((size_t)(rowbase + jj) << 8) + ky * 8 + q] = v;
            }
        }
    } else {
        // role L: lower[t] row j, col i=j+off: -w_t[i] M_t[i,j]; values inline
        const size_t matL = ((size_t)(b * 3 + 1) * NT + t) << 18;
        #pragma unroll
        for (int pass = 0; pass < 3; ++pass) {
            const int idx = tid + pass * 256;     // 768 quads
            const int jj = idx / 24, r = idx % 24;
            const int s = r >> 3, q = r & 7;      // neighbor offset (s-1, ddx)
            const int ky = jy - 1 + s;
            if (ky >= 0 && ky < NY) {
                f32x4 v = {0.f, 0.f, 0.f, 0.f};
                #pragma unroll
                for (int cq = 0; cq < 4; ++cq) {
                    const int ddx = q * 4 + cq - jj;
                    if (ddx >= -1 && ddx <= 1) {
                        const int d = s * 3 + (ddx + 1);
                        v[cq] = -sw[s][jj + 1 + ddx] * sc[s][jj + 1 + ddx][8 - d];
                    }
                }
                outq[matL + ((size_t)(rowbase + jj) << 8) + ky * 8 + q] = v;
            }
        }
    }
}

extern "C" void kernel_launch(void* const* d_in, const int* in_sizes, int n_in,
                              void* d_out, int out_size, void* d_ws, size_t ws_size,
                              hipStream_t stream) {
    (void)n_in; (void)d_ws; (void)ws_size;
    const float* kap = (const float*)d_in[0];  // [n_b,1,N,NT]
    const float* m   = (const float*)d_in[1];  // [n_b,2,N,NT]
    const float* H   = (const float*)d_in[2];  // [n_b,2,2,N,NT]
    const float* tau = (const float*)d_in[3];  // [n_b,1,N,NT]
    float* out = (float*)d_out;                // [n_b,3,NT,N,N]

    const int n_b = in_sizes[0] / (NN * NT);

    // Phase 1: zero the whole output (fast fill path; CU full-write kernels
    // cap at ~2.5 TB/s on this buffer across 4 structurally distinct designs).
    hipMemsetAsync(d_out, 0, (size_t)out_size, stream);

    // Phase 2: role-split band scatter, one short block per (b, t, jy, role).
    const int grid = n_b * NT * NY * 3;
    spde_scatter3<<<grid, 256, 0, stream>>>(kap, m, H, tau, out);
}

// Round 8
// 188.289 us; speedup vs baseline: 1.0773x; 1.0063x over previous
//
#include <hip/hip_runtime.h>

#define NT 8
#define NY 32
#define NX 32
#define NN 1024  // NY*NX

typedef __attribute__((ext_vector_type(4))) float f32x4;

// Stencil coefficients of M = I + A for one node. c[(ry+1)*3+(rx+1)] is the
// coefficient toward target offset (ry,rx); zeroed when the TARGET node falls
// off-grid (matches reference `valid` masking on the column node).
__device__ __forceinline__ void node_coefs(const float* __restrict__ kap,
                                           const float* __restrict__ m,
                                           const float* __restrict__ H,
                                           const float* __restrict__ tau,
                                           int b, int node, int tc,
                                           int iy, int ix,
                                           float* c /*[9]*/, float& w) {
    const int base = node * NT + tc;                 // [.., node, t] layout, last dim NT
    const float kp  = kap[(b * NN) * NT + base];
    const float m1  = m[((b * 2 + 0) * NN) * NT + base];
    const float m2  = m[((b * 2 + 1) * NN) * NT + base];
    const float h11 = H[((b * 4 + 0) * NN) * NT + base];
    const float h12 = H[((b * 4 + 1) * NN) * NT + base];
    const float h22 = H[((b * 4 + 3) * NN) * NT + base];
    const float tv  = tau[(b * NN) * NT + base];
    w = 1.0f / (tv * tv);

    const float cxy = 0.5f * h12;
    const bool ym = iy > 0, yp = iy < NY - 1;
    const bool xm = ix > 0, xp = ix < NX - 1;

    c[4] = 1.0f + kp * kp + 2.0f * h11 + 2.0f * h22;
    c[0] = (ym && xm) ? -cxy               : 0.0f;
    c[1] =  ym        ? (-h22 - 0.5f * m2) : 0.0f;
    c[2] = (ym && xp) ?  cxy               : 0.0f;
    c[3] =  xm        ? (-h11 - 0.5f * m1) : 0.0f;
    c[5] =  xp        ? (-h11 + 0.5f * m1) : 0.0f;
    c[6] = (yp && xm) ?  cxy               : 0.0f;
    c[7] =  yp        ? (-h22 + 0.5f * m2) : 0.0f;
    c[8] = (yp && xp) ? -cxy               : 0.0f;
}

// Merged scatter over a pre-zeroed output. ONE 512-thread block per (b,t,jy):
//   phase A : halo coefs (3x34 nodes, loaded once) -> LDS      [waves 0-1]
//   barrier
//   phase B : waves 0-3 compute 800 D band values -> LDS
//             waves 4-5 store upper[t-1] inline from halo LDS  (t>=1)
//             waves 6-7 store lower[t]   inline from halo LDS  (t>=1)
//   barrier
//   phase C : all 8 waves store D's 1280 quads (3 passes)
// All stores are full 128B ky-segments (8 lanes x float4). L[0]/U[7] remain
// memset-zero.
__global__ __launch_bounds__(512) void spde_scatter_m(const float* __restrict__ kap,
                                                      const float* __restrict__ m,
                                                      const float* __restrict__ H,
                                                      const float* __restrict__ tau,
                                                      float* __restrict__ out) {
    __shared__ float sc[3][34][9];   // coefs of node (jy-1+ly, lx-1); halo zeroed
    __shared__ float sw[3][34];      // w at those nodes (0 off-grid)
    __shared__ float valsD[32][25];

    const int gb  = blockIdx.x;      // (b*NT + t)*NY + jy
    const int jy  = gb & 31;
    const int t   = (gb >> 5) & 7;
    const int b   = gb >> 8;
    const int tid = threadIdx.x;

    f32x4* const outq = (f32x4*)out;
    const int rowbase = jy * NX;

    // phase A: coefs for grid rows jy-1..jy+1, x = -1..32 (102 nodes)
    if (tid < 102) {
        const int ly = tid / 34, lx = tid % 34;
        const int iy = jy + ly - 1, ix = lx - 1;
        float c[9];
        float w = 0.0f;
        if (iy >= 0 && iy < NY && ix >= 0 && ix < NX) {
            node_coefs(kap, m, H, tau, b, iy * NX + ix, t, iy, ix, c, w);
        } else {
            #pragma unroll
            for (int q = 0; q < 9; ++q) c[q] = 0.0f;
        }
        #pragma unroll
        for (int q = 0; q < 9; ++q) sc[ly][lx][q] = c[q];
        sw[ly][lx] = w;
    }
    __syncthreads();

    if (tid < 256) {
        // phase B-D: 800 D values (32 j x 25) over 256 threads
        #pragma unroll
        for (int pass = 0; pass < 4; ++pass) {
            const int e = tid + pass * 256;
            if (e < 800) {
                const int jj = e / 25, l = e % 25;
                const int dy = l / 5 - 2, dx = l % 5 - 2;
                float acc = 0.0f;
                #pragma unroll
                for (int d = 0; d < 9; ++d) {     // source rows i = j + off_d
                    const int ey = d / 3 - 1, ex = d % 3 - 1;
                    const int r2y = dy - ey, r2x = dx - ex;
                    if (r2y >= -1 && r2y <= 1 && r2x >= -1 && r2x <= 1) {
                        const float* ci = sc[ey + 1][jj + 1 + ex];
                        acc += sw[ey + 1][jj + 1 + ex] * ci[8 - d]
                                                       * ci[(r2y + 1) * 3 + (r2x + 1)];
                    }
                }
                if (l == 12 && t < NT - 1) {      // diagonal: + w_{t+1}[j]
                    const int j = rowbase + jj;
                    const float tv = tau[((size_t)b * NN + j) * NT + (t + 1)];
                    acc += 1.0f / (tv * tv);
                }
                valsD[jj][l] = acc;
            }
        }
    } else if (tid < 384) {
        // phase B-U: upper[t-1] row j: -w_t[j] M_t[j,k]; inline from halo
        if (t >= 1) {
            const size_t matU = ((size_t)(b * 3 + 2) * NT + (t - 1)) << 18;
            const int lt = tid - 256;             // 128 threads, 768 quads, 6 passes
            #pragma unroll
            for (int pass = 0; pass < 6; ++pass) {
                const int idx = lt + pass * 128;
                const int jj = idx / 24, r = idx % 24;
                const int s = r >> 3, q = r & 7;
                const int ky = jy - 1 + s;
                if (ky >= 0 && ky < NY) {
                    f32x4 v = {0.f, 0.f, 0.f, 0.f};
                    #pragma unroll
                    for (int cq = 0; cq < 4; ++cq) {
                        const int ddx = q * 4 + cq - jj;
                        if (ddx >= -1 && ddx <= 1) {
                            v[cq] = -sw[1][jj + 1] * sc[1][jj + 1][s * 3 + (ddx + 1)];
                        }
                    }
                    outq[matU + ((size_t)(rowbase + jj) << 8) + ky * 8 + q] = v;
                }
            }
        }
    } else {
        // phase B-L: lower[t] row j, col i=j+(s-1,ddx): -w_t[i] M_t[i,j]; inline
        if (t >= 1) {
            const size_t matL = ((size_t)(b * 3 + 1) * NT + t) << 18;
            const int lt = tid - 384;             // 128 threads, 768 quads, 6 passes
            #pragma unroll
            for (int pass = 0; pass < 6; ++pass) {
                const int idx = lt + pass * 128;
                const int jj = idx / 24, r = idx % 24;
                const int s = r >> 3, q = r & 7;
                const int ky = jy - 1 + s;
                if (ky >= 0 && ky < NY) {
                    f32x4 v = {0.f, 0.f, 0.f, 0.f};
                    #pragma unroll
                    for (int cq = 0; cq < 4; ++cq) {
                        const int ddx = q * 4 + cq - jj;
                        if (ddx >= -1 && ddx <= 1) {
                            const int d = s * 3 + (ddx + 1);
                            v[cq] = -sw[s][jj + 1 + ddx] * sc[s][jj + 1 + ddx][8 - d];
                        }
                    }
                    outq[matL + ((size_t)(rowbase + jj) << 8) + ky * 8 + q] = v;
                }
            }
        }
    }
    __syncthreads();

    // phase C: D stores, 1280 quads over 512 threads (3 passes)
    const size_t matD = ((size_t)(b * 3 + 0) * NT + t) << 18;
    #pragma unroll
    for (int pass = 0; pass < 3; ++pass) {
        const int idx = tid + pass * 512;
        if (idx < 1280) {
            const int jj = idx / 40, r = idx % 40;
            const int s = r >> 3, q = r & 7;
            const int ky = jy - 2 + s;
            if (ky >= 0 && ky < NY) {
                f32x4 v = {0.f, 0.f, 0.f, 0.f};
                #pragma unroll
                for (int cq = 0; cq < 4; ++cq) {
                    const int ddx = q * 4 + cq - jj;
                    if (ddx >= -2 && ddx <= 2) v[cq] = valsD[jj][s * 5 + (ddx + 2)];
                }
                outq[matD + ((size_t)(rowbase + jj) << 8) + ky * 8 + q] = v;
            }
        }
    }
}

extern "C" void kernel_launch(void* const* d_in, const int* in_sizes, int n_in,
                              void* d_out, int out_size, void* d_ws, size_t ws_size,
                              hipStream_t stream) {
    (void)n_in; (void)d_ws; (void)ws_size;
    const float* kap = (const float*)d_in[0];  // [n_b,1,N,NT]
    const float* m   = (const float*)d_in[1];  // [n_b,2,N,NT]
    const float* H   = (const float*)d_in[2];  // [n_b,2,2,N,NT]
    const float* tau = (const float*)d_in[3];  // [n_b,1,N,NT]
    float* out = (float*)d_out;                // [n_b,3,NT,N,N]

    const int n_b = in_sizes[0] / (NN * NT);

    // Phase 1: zero the whole output (fast fill path; CU full-write kernels
    // cap at ~2.5 TB/s on this buffer across 4 structurally distinct designs).
    hipMemsetAsync(d_out, 0, (size_t)out_size, stream);

    // Phase 2: merged band scatter, one 512-thread block per (b, t, jy).
    const int grid = n_b * NT * NY;
    spde_scatter_m<<<grid, 512, 0, stream>>>(kap, m, H, tau, out);
}